// Round 1
// baseline (1817.905 us; speedup 1.0000x reference)
//
#include <hip/hip_runtime.h>

#define BN 1024
#define SN 49
#define DN 128
#define HN 4
#define VN 100001
#define BSN (BN*SN)          // 50176 = 784 * 64
#define NEGF (-1e8f)

// ---------------------------------------------------------------------------
// k_qkv: fused embedding+posenc + 3 projections.  grid 784, block 256.
// Each block handles 64 rows of x (= [BS, D]); x tile kept TRANSPOSED in LDS.
// ---------------------------------------------------------------------------
__global__ __launch_bounds__(256) void k_qkv(
    const int* __restrict__ seq, const int* __restrict__ sub,
    const float* __restrict__ emb, const float* __restrict__ subg,
    const float* __restrict__ wq, const float* __restrict__ bq,
    const float* __restrict__ wk, const float* __restrict__ bk,
    const float* __restrict__ wv, const float* __restrict__ bv,
    float* __restrict__ q, float* __restrict__ k, float* __restrict__ v)
{
    __shared__ float xT[DN][68];     // [k][s], stride 68 keeps 16B alignment
    __shared__ float wl[32][DN];     // one K-tile of the weight
    const int tid  = threadIdx.x;
    const int row0 = blockIdx.x * 64;

    // embed + positional encoding, stored transposed
    for (int i = tid; i < 64 * DN; i += 256) {
        int s = i >> 7, c = i & 127;
        int row = row0 + s;
        int tok = seq[row], st = sub[row];
        int p = row % SN;
        float pe = ((c & 1) == 0) ? sinf((float)p) : cosf((float)p);
        xT[c][s] = emb[tok * DN + c] + subg[st * DN + c] + pe;
    }

    const int s0 = (tid >> 5) << 3;   // 0,8,...,56
    const int d0 = (tid & 31) << 2;   // 0,4,...,124
    const float* Wm[3] = {wq, wk, wv};
    const float* Bm[3] = {bq, bk, bv};
    float*       Om[3] = {q,  k,  v};

#pragma unroll
    for (int m = 0; m < 3; ++m) {
        float acc[8][4];
#pragma unroll
        for (int i = 0; i < 8; ++i)
#pragma unroll
            for (int j = 0; j < 4; ++j) acc[i][j] = 0.f;

        for (int kt = 0; kt < 4; ++kt) {
            __syncthreads();                       // guards xT (first) / wl reuse
            const float* wp = Wm[m] + kt * 32 * DN;
            for (int i = tid; i < 32 * DN; i += 256)
                ((float*)wl)[i] = wp[i];
            __syncthreads();
#pragma unroll
            for (int kk = 0; kk < 32; ++kk) {
                const int kg = kt * 32 + kk;
                float4 xa = *(const float4*)&xT[kg][s0];
                float4 xb = *(const float4*)&xT[kg][s0 + 4];
                float4 w4 = *(const float4*)&wl[kk][d0];
                float xr[8] = {xa.x, xa.y, xa.z, xa.w, xb.x, xb.y, xb.z, xb.w};
                float wr[4] = {w4.x, w4.y, w4.z, w4.w};
#pragma unroll
                for (int i = 0; i < 8; ++i)
#pragma unroll
                    for (int j = 0; j < 4; ++j) acc[i][j] += xr[i] * wr[j];
            }
        }
        float4 bb = *(const float4*)&Bm[m][d0];
#pragma unroll
        for (int i = 0; i < 8; ++i) {
            float4 o = {acc[i][0] + bb.x, acc[i][1] + bb.y,
                        acc[i][2] + bb.z, acc[i][3] + bb.w};
            *(float4*)&Om[m][(size_t)(row0 + s0 + i) * DN + d0] = o;
        }
    }
}

// ---------------------------------------------------------------------------
// k_attn: one (batch, head) per block.  grid 4096, block 64.
// ---------------------------------------------------------------------------
__global__ __launch_bounds__(64) void k_attn(
    const float* __restrict__ q, const float* __restrict__ k,
    const float* __restrict__ v, const int* __restrict__ seq,
    float* __restrict__ av)
{
    __shared__ float qt[SN][33], ktl[SN][33], vt[SN][33];
    __shared__ float sc[SN][50];
    __shared__ int   ss[SN];
    const int b = blockIdx.x >> 2, h = blockIdx.x & 3;
    const int tid = threadIdx.x;
    const size_t base = (size_t)(b * SN) * DN + h * 32;

    if (tid < SN) ss[tid] = seq[b * SN + tid];
    for (int i = tid; i < SN * 32; i += 64) {
        int s = i >> 5, d = i & 31;
        qt[s][d]  = q[base + s * DN + d];
        ktl[s][d] = k[base + s * DN + d];
        vt[s][d]  = v[base + s * DN + d];
    }
    __syncthreads();

    for (int i = tid; i < SN * SN; i += 64) {
        int r = i / SN, c = i - r * SN;
        float a = 0.f;
#pragma unroll
        for (int d = 0; d < 32; ++d) a += qt[r][d] * ktl[c][d];
        a *= (1.f / 32.f);
        sc[r][c] = (ss[r] == 0 || ss[c] == 0) ? NEGF : a;
    }
    __syncthreads();

    if (tid < SN) {
        float m = -3.4e38f;
        for (int j = 0; j < SN; ++j) m = fmaxf(m, sc[tid][j]);
        float sum = 0.f;
        for (int j = 0; j < SN; ++j) {
            float e = __expf(sc[tid][j] - m);
            sc[tid][j] = e; sum += e;
        }
        float inv = 1.f / sum;
        for (int j = 0; j < SN; ++j) sc[tid][j] *= inv;
    }
    __syncthreads();

    for (int i = tid; i < SN * 32; i += 64) {
        int s = i >> 5, d = i & 31;
        float a = 0.f;
        for (int j = 0; j < SN; ++j) a += sc[s][j] * vt[j][d];
        av[base + s * DN + d] = a;
    }
}

// ---------------------------------------------------------------------------
// k_enc: enc = av @ wo + bo.  grid 784, block 256 (same tiling as k_qkv).
// ---------------------------------------------------------------------------
__global__ __launch_bounds__(256) void k_enc(
    const float* __restrict__ av, const float* __restrict__ wo,
    const float* __restrict__ bo, float* __restrict__ enc)
{
    __shared__ float xT[DN][68];
    __shared__ float wl[32][DN];
    const int tid  = threadIdx.x;
    const int row0 = blockIdx.x * 64;

    for (int i = tid; i < 64 * DN; i += 256) {
        int s = i >> 7, c = i & 127;
        xT[c][s] = av[(size_t)(row0 + s) * DN + c];
    }

    const int s0 = (tid >> 5) << 3;
    const int d0 = (tid & 31) << 2;
    float acc[8][4];
#pragma unroll
    for (int i = 0; i < 8; ++i)
#pragma unroll
        for (int j = 0; j < 4; ++j) acc[i][j] = 0.f;

    for (int kt = 0; kt < 4; ++kt) {
        __syncthreads();
        const float* wp = wo + kt * 32 * DN;
        for (int i = tid; i < 32 * DN; i += 256)
            ((float*)wl)[i] = wp[i];
        __syncthreads();
#pragma unroll
        for (int kk = 0; kk < 32; ++kk) {
            const int kg = kt * 32 + kk;
            float4 xa = *(const float4*)&xT[kg][s0];
            float4 xb = *(const float4*)&xT[kg][s0 + 4];
            float4 w4 = *(const float4*)&wl[kk][d0];
            float xr[8] = {xa.x, xa.y, xa.z, xa.w, xb.x, xb.y, xb.z, xb.w};
            float wr[4] = {w4.x, w4.y, w4.z, w4.w};
#pragma unroll
            for (int i = 0; i < 8; ++i)
#pragma unroll
                for (int j = 0; j < 4; ++j) acc[i][j] += xr[i] * wr[j];
        }
    }
    float4 bb = *(const float4*)&bo[d0];
#pragma unroll
    for (int i = 0; i < 8; ++i) {
        float4 o = {acc[i][0] + bb.x, acc[i][1] + bb.y,
                    acc[i][2] + bb.z, acc[i][3] + bb.w};
        *(float4*)&enc[(size_t)(row0 + s0 + i) * DN + d0] = o;
    }
}

// ---------------------------------------------------------------------------
// k_pool: per batch, w = enc@w_enc+b_enc; pooledT[d][b] = sum_s w[s]*enc[s][d]
// grid 1024, block 128.
// ---------------------------------------------------------------------------
__global__ __launch_bounds__(128) void k_pool(
    const float* __restrict__ enc, const float* __restrict__ w_enc,
    const float* __restrict__ b_enc, float* __restrict__ pT)
{
    __shared__ float es[SN][129];
    __shared__ float wrow[SN];
    const int b = blockIdx.x, tid = threadIdx.x;

    for (int i = tid; i < SN * DN; i += 128) {
        int s = i >> 7, d = i & 127;
        es[s][d] = enc[(size_t)(b * SN + s) * DN + d];
    }
    __syncthreads();
    if (tid < SN) {
        float a = b_enc[0];
        for (int d = 0; d < DN; ++d) a += es[tid][d] * w_enc[d];
        wrow[tid] = a;
    }
    __syncthreads();
    {
        float a = 0.f;
        for (int s = 0; s < SN; ++s) a += wrow[s] * es[s][tid];
        pT[(size_t)tid * BN + b] = a;
    }
}

// ---------------------------------------------------------------------------
// k_novel: out[b][v] = pooled[b]·w_score[:,v] + b_score[v].
// grid (391, 128), block 256.  Each thread: 1 v, 8 batches.
// pooled read transposed -> wave-uniform scalar loads.
// ---------------------------------------------------------------------------
__global__ __launch_bounds__(256) void k_novel(
    const float* __restrict__ pT, const float* __restrict__ w_score,
    const float* __restrict__ b_score, float* __restrict__ out)
{
    const int vv = blockIdx.x * 256 + threadIdx.x;
    const int vc = vv < VN ? vv : VN - 1;
    const int b0 = blockIdx.y * 8;
    float acc[8] = {0.f, 0.f, 0.f, 0.f, 0.f, 0.f, 0.f, 0.f};

#pragma unroll 4
    for (int d = 0; d < DN; ++d) {
        float w = w_score[(size_t)d * VN + vc];
        const float* p = &pT[(size_t)d * BN + b0];   // wave-uniform
#pragma unroll
        for (int i = 0; i < 8; ++i) acc[i] += p[i] * w;
    }
    if (vv < VN) {
        float bs = b_score[vc];
#pragma unroll
        for (int i = 0; i < 8; ++i)
            out[(size_t)(b0 + i) * VN + vv] = acc[i] + bs;
    }
}

// ---------------------------------------------------------------------------
// k_mask: out[b][seq[b][s]] = NEG
// ---------------------------------------------------------------------------
__global__ __launch_bounds__(64) void k_mask(
    const int* __restrict__ seq, float* __restrict__ out)
{
    const int b = blockIdx.x, tid = threadIdx.x;
    if (tid < SN) {
        int t = seq[b * SN + tid];
        out[(size_t)b * VN + t] = NEGF;
    }
}

// ---------------------------------------------------------------------------
extern "C" void kernel_launch(void* const* d_in, const int* in_sizes, int n_in,
                              void* d_out, int out_size, void* d_ws, size_t ws_size,
                              hipStream_t stream)
{
    (void)in_sizes; (void)n_in; (void)out_size; (void)ws_size;
    const int*   seq  = (const int*)d_in[0];
    const int*   sub  = (const int*)d_in[1];
    const float* emb  = (const float*)d_in[2];
    const float* subg = (const float*)d_in[3];
    const float* wq   = (const float*)d_in[4];
    const float* bq   = (const float*)d_in[5];
    const float* wk   = (const float*)d_in[6];
    const float* bk   = (const float*)d_in[7];
    const float* wv   = (const float*)d_in[8];
    const float* bv   = (const float*)d_in[9];
    const float* wo   = (const float*)d_in[10];
    const float* bo   = (const float*)d_in[11];
    const float* wenc = (const float*)d_in[12];
    const float* benc = (const float*)d_in[13];
    const float* wsc  = (const float*)d_in[14];
    const float* bsc  = (const float*)d_in[15];
    float* out = (float*)d_out;

    const size_t NBSD = (size_t)BSN * DN;
    float* Q  = (float*)d_ws;
    float* K  = Q  + NBSD;
    float* Vb = K  + NBSD;
    float* AV = Vb + NBSD;
    float* PT = AV + NBSD;
    float* ENC = Q;                 // reuse Q buffer after attention

    k_qkv<<<784, 256, 0, stream>>>(seq, sub, emb, subg,
                                   wq, bq, wk, bk, wv, bv, Q, K, Vb);
    k_attn<<<4096, 64, 0, stream>>>(Q, K, Vb, seq, AV);
    k_enc<<<784, 256, 0, stream>>>(AV, wo, bo, ENC);
    k_pool<<<1024, 128, 0, stream>>>(ENC, wenc, benc, PT);
    dim3 g6(391, 128);
    k_novel<<<g6, 256, 0, stream>>>(PT, wsc, bsc, out);
    k_mask<<<1024, 64, 0, stream>>>(seq, out);
}

// Round 4
// 949.964 us; speedup vs baseline: 1.9137x; 1.9137x over previous
//
#include <hip/hip_runtime.h>

#define BN 1024
#define SN 49
#define DN 128
#define HN 4
#define VN 100001
#define BSN (BN*SN)          // 50176 = 784 * 64
#define NEGF (-1e8f)

typedef __attribute__((ext_vector_type(8))) short bf16x8;
typedef __attribute__((ext_vector_type(4))) float f32x4;

__device__ inline short f2bf(float f) {
    unsigned u = __builtin_bit_cast(unsigned, f);
    unsigned r = (u + 0x7fffu + ((u >> 16) & 1u)) >> 16;
    return (short)r;
}

// ---------------------------------------------------------------------------
// k_qkv: fused embedding+posenc + 3 projections.  grid 784, block 256.
// ---------------------------------------------------------------------------
__global__ __launch_bounds__(256) void k_qkv(
    const int* __restrict__ seq, const int* __restrict__ sub,
    const float* __restrict__ emb, const float* __restrict__ subg,
    const float* __restrict__ wq, const float* __restrict__ bq,
    const float* __restrict__ wk, const float* __restrict__ bk,
    const float* __restrict__ wv, const float* __restrict__ bv,
    float* __restrict__ q, float* __restrict__ k, float* __restrict__ v)
{
    __shared__ float xT[DN][68];     // [k][s], stride 68 keeps 16B alignment
    __shared__ float wl[32][DN];     // one K-tile of the weight
    const int tid  = threadIdx.x;
    const int row0 = blockIdx.x * 64;

    for (int i = tid; i < 64 * DN; i += 256) {
        int s = i >> 7, c = i & 127;
        int row = row0 + s;
        int tok = seq[row], st = sub[row];
        int p = row % SN;
        float pe = ((c & 1) == 0) ? sinf((float)p) : cosf((float)p);
        xT[c][s] = emb[tok * DN + c] + subg[st * DN + c] + pe;
    }

    const int s0 = (tid >> 5) << 3;   // 0,8,...,56
    const int d0 = (tid & 31) << 2;   // 0,4,...,124
    const float* Wm[3] = {wq, wk, wv};
    const float* Bm[3] = {bq, bk, bv};
    float*       Om[3] = {q,  k,  v};

#pragma unroll
    for (int m = 0; m < 3; ++m) {
        float acc[8][4];
#pragma unroll
        for (int i = 0; i < 8; ++i)
#pragma unroll
            for (int j = 0; j < 4; ++j) acc[i][j] = 0.f;

        for (int kt = 0; kt < 4; ++kt) {
            __syncthreads();
            const float* wp = Wm[m] + kt * 32 * DN;
            for (int i = tid; i < 32 * DN; i += 256)
                ((float*)wl)[i] = wp[i];
            __syncthreads();
#pragma unroll
            for (int kk = 0; kk < 32; ++kk) {
                const int kg = kt * 32 + kk;
                float4 xa = *(const float4*)&xT[kg][s0];
                float4 xb = *(const float4*)&xT[kg][s0 + 4];
                float4 w4 = *(const float4*)&wl[kk][d0];
                float xr[8] = {xa.x, xa.y, xa.z, xa.w, xb.x, xb.y, xb.z, xb.w};
                float wr[4] = {w4.x, w4.y, w4.z, w4.w};
#pragma unroll
                for (int i = 0; i < 8; ++i)
#pragma unroll
                    for (int j = 0; j < 4; ++j) acc[i][j] += xr[i] * wr[j];
            }
        }
        float4 bb = *(const float4*)&Bm[m][d0];
#pragma unroll
        for (int i = 0; i < 8; ++i) {
            float4 o = {acc[i][0] + bb.x, acc[i][1] + bb.y,
                        acc[i][2] + bb.z, acc[i][3] + bb.w};
            *(float4*)&Om[m][(size_t)(row0 + s0 + i) * DN + d0] = o;
        }
    }
}

// ---------------------------------------------------------------------------
// k_attn: one (batch, head) per block.  grid 4096, block 64.
// ---------------------------------------------------------------------------
__global__ __launch_bounds__(64) void k_attn(
    const float* __restrict__ q, const float* __restrict__ k,
    const float* __restrict__ v, const int* __restrict__ seq,
    float* __restrict__ av)
{
    __shared__ float qt[SN][33], ktl[SN][33], vt[SN][33];
    __shared__ float sc[SN][50];
    __shared__ int   ss[SN];
    const int b = blockIdx.x >> 2, h = blockIdx.x & 3;
    const int tid = threadIdx.x;
    const size_t base = (size_t)(b * SN) * DN + h * 32;

    if (tid < SN) ss[tid] = seq[b * SN + tid];
    for (int i = tid; i < SN * 32; i += 64) {
        int s = i >> 5, d = i & 31;
        qt[s][d]  = q[base + s * DN + d];
        ktl[s][d] = k[base + s * DN + d];
        vt[s][d]  = v[base + s * DN + d];
    }
    __syncthreads();

    for (int i = tid; i < SN * SN; i += 64) {
        int r = i / SN, c = i - r * SN;
        float a = 0.f;
#pragma unroll
        for (int d = 0; d < 32; ++d) a += qt[r][d] * ktl[c][d];
        a *= (1.f / 32.f);
        sc[r][c] = (ss[r] == 0 || ss[c] == 0) ? NEGF : a;
    }
    __syncthreads();

    if (tid < SN) {
        float m = -3.4e38f;
        for (int j = 0; j < SN; ++j) m = fmaxf(m, sc[tid][j]);
        float sum = 0.f;
        for (int j = 0; j < SN; ++j) {
            float e = __expf(sc[tid][j] - m);
            sc[tid][j] = e; sum += e;
        }
        float inv = 1.f / sum;
        for (int j = 0; j < SN; ++j) sc[tid][j] *= inv;
    }
    __syncthreads();

    for (int i = tid; i < SN * 32; i += 64) {
        int s = i >> 5, d = i & 31;
        float a = 0.f;
        for (int j = 0; j < SN; ++j) a += sc[s][j] * vt[j][d];
        av[base + s * DN + d] = a;
    }
}

// ---------------------------------------------------------------------------
// k_enc: enc = av @ wo + bo.  grid 784, block 256.
// ---------------------------------------------------------------------------
__global__ __launch_bounds__(256) void k_enc(
    const float* __restrict__ av, const float* __restrict__ wo,
    const float* __restrict__ bo, float* __restrict__ enc)
{
    __shared__ float xT[DN][68];
    __shared__ float wl[32][DN];
    const int tid  = threadIdx.x;
    const int row0 = blockIdx.x * 64;

    for (int i = tid; i < 64 * DN; i += 256) {
        int s = i >> 7, c = i & 127;
        xT[c][s] = av[(size_t)(row0 + s) * DN + c];
    }

    const int s0 = (tid >> 5) << 3;
    const int d0 = (tid & 31) << 2;
    float acc[8][4];
#pragma unroll
    for (int i = 0; i < 8; ++i)
#pragma unroll
        for (int j = 0; j < 4; ++j) acc[i][j] = 0.f;

    for (int kt = 0; kt < 4; ++kt) {
        __syncthreads();
        const float* wp = wo + kt * 32 * DN;
        for (int i = tid; i < 32 * DN; i += 256)
            ((float*)wl)[i] = wp[i];
        __syncthreads();
#pragma unroll
        for (int kk = 0; kk < 32; ++kk) {
            const int kg = kt * 32 + kk;
            float4 xa = *(const float4*)&xT[kg][s0];
            float4 xb = *(const float4*)&xT[kg][s0 + 4];
            float4 w4 = *(const float4*)&wl[kk][d0];
            float xr[8] = {xa.x, xa.y, xa.z, xa.w, xb.x, xb.y, xb.z, xb.w};
            float wr[4] = {w4.x, w4.y, w4.z, w4.w};
#pragma unroll
            for (int i = 0; i < 8; ++i)
#pragma unroll
                for (int j = 0; j < 4; ++j) acc[i][j] += xr[i] * wr[j];
        }
    }
    float4 bb = *(const float4*)&bo[d0];
#pragma unroll
    for (int i = 0; i < 8; ++i) {
        float4 o = {acc[i][0] + bb.x, acc[i][1] + bb.y,
                    acc[i][2] + bb.z, acc[i][3] + bb.w};
        *(float4*)&enc[(size_t)(row0 + s0 + i) * DN + d0] = o;
    }
}

// ---------------------------------------------------------------------------
// k_pool: per batch b: w = enc@w_enc+b_enc; pooled[b][d] = sum_s w[s]*enc[s][d]
// writes pooled in bf16 MFMA A-fragment order.  grid 1024, block 128.
// A-frag layout: value (row=b, k=d) -> frag = (b/16)*4 + d/32,
//                lane = ((d/8)%4)*16 + b%16, byte j = d%8.
// ---------------------------------------------------------------------------
__global__ __launch_bounds__(128) void k_pool(
    const float* __restrict__ enc, const float* __restrict__ w_enc,
    const float* __restrict__ b_enc, short* __restrict__ pa)
{
    __shared__ float es[SN][129];
    __shared__ float wrow[SN];
    const int b = blockIdx.x, tid = threadIdx.x;

    for (int i = tid; i < SN * DN; i += 128) {
        int s = i >> 7, d = i & 127;
        es[s][d] = enc[(size_t)(b * SN + s) * DN + d];
    }
    __syncthreads();
    if (tid < SN) {
        float a = b_enc[0];
        for (int d = 0; d < DN; ++d) a += es[tid][d] * w_enc[d];
        wrow[tid] = a;
    }
    __syncthreads();
    {
        const int d = tid;
        float a = 0.f;
        for (int s = 0; s < SN; ++s) a += wrow[s] * es[s][d];
        int frag = (b >> 4) * 4 + (d >> 5);
        int lane = ((d >> 3) & 3) * 16 + (b & 15);
        pa[frag * 512 + lane * 8 + (d & 7)] = f2bf(a);
    }
}

// ---------------------------------------------------------------------------
// k_prepw: w_score fp32 [128][VN] -> bf16 B-fragment order, zero-padded cols.
// One block = one 16-col group (g16 = blockIdx.x), all 128 k.
// value (k, c): frag = g16*4 + k/32, lane = ((k/8)%4)*16 + c%16, byte = k%8.
// Thread t: c = g16*16 + t%16, k = (t/16)*8 + j  -> one contiguous short8.
// grid 6252 (= ceil(100001/16)), block 256.
// ---------------------------------------------------------------------------
__global__ __launch_bounds__(256) void k_prepw(
    const float* __restrict__ wsc, short* __restrict__ pf)
{
    const int bx = blockIdx.x, t = threadIdx.x;
    const int c = bx * 16 + (t & 15);
    const int kg = t >> 4;            // 0..15
    bf16x8 s;
#pragma unroll
    for (int j = 0; j < 8; ++j) {
        int k = kg * 8 + j;
        float v = (c < VN) ? wsc[(size_t)k * VN + c] : 0.f;
        s[j] = f2bf(v);
    }
    const int base = (bx * 4 + (t >> 6)) * 512 + ((t >> 4) & 3) * 128 + (t & 15) * 8;
    *(bf16x8*)(pf + base) = s;
}

// ---------------------------------------------------------------------------
// k_novel: out[b][v] = pooled[b] . w_score[:,v] + b_score[v], via bf16 MFMA.
// block 256 = 4 waves; wave = 32 rows x 64 cols; block tile 128 x 64.
// grid (1563, 8).  All operand loads are wave-linear 16B/lane bursts.
// ---------------------------------------------------------------------------
__global__ __launch_bounds__(256) void k_novel(
    const short* __restrict__ pa, const short* __restrict__ pf,
    const float* __restrict__ bsc, float* __restrict__ out)
{
    const int t = threadIdx.x;
    const int w = t >> 6, l = t & 63;
    const int bx = blockIdx.x, by = blockIdx.y;
    const bf16x8* A = (const bf16x8*)pa;   // vec idx = frag*64 + lane
    const bf16x8* Bv = (const bf16x8*)pf;

    const int a0 = (by * 8 + w * 2) * 256 + l;   // mf stride 256, ks stride 64
    const int b0 = bx * 1024 + l;                // nf stride 256, ks stride 64

    f32x4 acc[2][4];
#pragma unroll
    for (int mf = 0; mf < 2; ++mf)
#pragma unroll
        for (int nf = 0; nf < 4; ++nf) acc[mf][nf] = (f32x4){0.f, 0.f, 0.f, 0.f};

#pragma unroll
    for (int ks = 0; ks < 4; ++ks) {
        bf16x8 af0 = A[a0 + ks * 64];
        bf16x8 af1 = A[a0 + 256 + ks * 64];
        bf16x8 bf0 = Bv[b0 + ks * 64];
        bf16x8 bf1 = Bv[b0 + 256 + ks * 64];
        bf16x8 bf2 = Bv[b0 + 512 + ks * 64];
        bf16x8 bf3 = Bv[b0 + 768 + ks * 64];
        acc[0][0] = __builtin_amdgcn_mfma_f32_16x16x32_bf16(af0, bf0, acc[0][0], 0, 0, 0);
        acc[0][1] = __builtin_amdgcn_mfma_f32_16x16x32_bf16(af0, bf1, acc[0][1], 0, 0, 0);
        acc[0][2] = __builtin_amdgcn_mfma_f32_16x16x32_bf16(af0, bf2, acc[0][2], 0, 0, 0);
        acc[0][3] = __builtin_amdgcn_mfma_f32_16x16x32_bf16(af0, bf3, acc[0][3], 0, 0, 0);
        acc[1][0] = __builtin_amdgcn_mfma_f32_16x16x32_bf16(af1, bf0, acc[1][0], 0, 0, 0);
        acc[1][1] = __builtin_amdgcn_mfma_f32_16x16x32_bf16(af1, bf1, acc[1][1], 0, 0, 0);
        acc[1][2] = __builtin_amdgcn_mfma_f32_16x16x32_bf16(af1, bf2, acc[1][2], 0, 0, 0);
        acc[1][3] = __builtin_amdgcn_mfma_f32_16x16x32_bf16(af1, bf3, acc[1][3], 0, 0, 0);
    }

    const int cb = bx * 64 + (l & 15);
    const int rb = by * 128 + w * 32 + ((l >> 4) << 2);
#pragma unroll
    for (int nf = 0; nf < 4; ++nf) {
        int col = cb + nf * 16;
        if (col >= VN) continue;
        float bias = bsc[col];
#pragma unroll
        for (int mf = 0; mf < 2; ++mf) {
            int row = rb + mf * 16;
#pragma unroll
            for (int i = 0; i < 4; ++i)
                out[(size_t)(row + i) * VN + col] = acc[mf][nf][i] + bias;
        }
    }
}

// ---------------------------------------------------------------------------
// k_mask: out[b][seq[b][s]] = NEG
// ---------------------------------------------------------------------------
__global__ __launch_bounds__(64) void k_mask(
    const int* __restrict__ seq, float* __restrict__ out)
{
    const int b = blockIdx.x, tid = threadIdx.x;
    if (tid < SN) {
        int t = seq[b * SN + tid];
        out[(size_t)b * VN + t] = NEGF;
    }
}

// ---------------------------------------------------------------------------
extern "C" void kernel_launch(void* const* d_in, const int* in_sizes, int n_in,
                              void* d_out, int out_size, void* d_ws, size_t ws_size,
                              hipStream_t stream)
{
    (void)in_sizes; (void)n_in; (void)out_size; (void)ws_size;
    const int*   seq  = (const int*)d_in[0];
    const int*   sub  = (const int*)d_in[1];
    const float* emb  = (const float*)d_in[2];
    const float* subg = (const float*)d_in[3];
    const float* wq   = (const float*)d_in[4];
    const float* bq   = (const float*)d_in[5];
    const float* wk   = (const float*)d_in[6];
    const float* bk   = (const float*)d_in[7];
    const float* wv   = (const float*)d_in[8];
    const float* bv   = (const float*)d_in[9];
    const float* wo   = (const float*)d_in[10];
    const float* bo   = (const float*)d_in[11];
    const float* wenc = (const float*)d_in[12];
    const float* benc = (const float*)d_in[13];
    const float* wsc  = (const float*)d_in[14];
    const float* bsc  = (const float*)d_in[15];
    float* out = (float*)d_out;

    const size_t NBSD = (size_t)BSN * DN;
    float* Q   = (float*)d_ws;
    float* K   = Q  + NBSD;
    float* Vb  = K  + NBSD;
    float* AV  = Vb + NBSD;
    short* PA  = (short*)(AV + NBSD);   // 256 KB, bf16 A-fragments
    float* ENC = Q;                     // reuse Q after attention
    short* PF  = (short*)K;             // reuse K after attention, 25.6 MB

    k_qkv<<<784, 256, 0, stream>>>(seq, sub, emb, subg,
                                   wq, bq, wk, bk, wv, bv, Q, K, Vb);
    k_attn<<<4096, 64, 0, stream>>>(Q, K, Vb, seq, AV);
    k_prepw<<<6252, 256, 0, stream>>>(wsc, PF);
    k_enc<<<784, 256, 0, stream>>>(AV, wo, bo, ENC);
    k_pool<<<1024, 128, 0, stream>>>(ENC, wenc, benc, PA);
    dim3 gn(1563, 8);
    k_novel<<<gn, 256, 0, stream>>>(PA, PF, bsc, out);
    k_mask<<<1024, 64, 0, stream>>>(seq, out);
}

// Round 5
// 730.483 us; speedup vs baseline: 2.4886x; 1.3005x over previous
//
#include <hip/hip_runtime.h>

#define BN 1024
#define SN 49
#define DN 128
#define HN 4
#define VN 100001
#define BSN (BN*SN)          // 50176 = 3136 * 16
#define RBN 3136             // row-blocks of 16
#define NEGF (-1e8f)

typedef __attribute__((ext_vector_type(8))) short bf16x8;
typedef __attribute__((ext_vector_type(4))) float f32x4;

__device__ inline short f2bf(float f) {
    unsigned u = __builtin_bit_cast(unsigned, f);
    unsigned r = (u + 0x7fffu + ((u >> 16) & 1u)) >> 16;
    return (short)r;
}
__device__ inline float bf2f(short s) {
    return __builtin_bit_cast(float, ((unsigned)(unsigned short)s) << 16);
}

// Fragment conventions (verified on HW by round-4 k_novel pass):
//  A-frag (M x K=128): value(row,k): frag=(row/16)*4 + k/32,
//      lane=((k/8)%4)*16 + row%16, byte=k%8.  stored frag*512+lane*8+byte.
//  B-frag (K=128 x N): value(k,c): frag=(c/16)*4 + k/32,
//      lane=((k/8)%4)*16 + c%16, byte=k%8.
//  C (16x16): lane l reg i -> row=4*(l/16)+i, col=l%16.

// ---------------------------------------------------------------------------
// k_prepw4: pack wq,wk,wv,wo [128k][128c] -> B-frag bf16.  grid 32, block 256.
// ---------------------------------------------------------------------------
__global__ __launch_bounds__(256) void k_prepw4(
    const float* __restrict__ wq, const float* __restrict__ wk,
    const float* __restrict__ wv, const float* __restrict__ wo,
    short* __restrict__ pw)
{
    const int bx = blockIdx.x, t = threadIdx.x;
    const int w = bx >> 3, g = bx & 7;
    const float* W = (w == 0) ? wq : (w == 1) ? wk : (w == 2) ? wv : wo;
    const int c = g * 16 + (t & 15);
    bf16x8 s;
#pragma unroll
    for (int j = 0; j < 8; ++j) {
        int k = (t >> 4) * 8 + j;
        s[j] = f2bf(W[k * DN + c]);
    }
    const int base = w * 32 * 512 + (g * 4 + (t >> 6)) * 512
                   + ((t >> 4) & 3) * 128 + (t & 15) * 8;
    *(bf16x8*)(pw + base) = s;
}

// ---------------------------------------------------------------------------
// k_embed: x = emb[seq] + subg[subtype] + posenc  ->  bf16 A-frag order.
// grid 3136 (one 16-row block), block 256.
// ---------------------------------------------------------------------------
__global__ __launch_bounds__(256) void k_embed(
    const int* __restrict__ seq, const int* __restrict__ sub,
    const float* __restrict__ emb, const float* __restrict__ subg,
    short* __restrict__ xa)
{
    const int t = threadIdx.x, rb = blockIdx.x;
    const int ks = t >> 6, l = t & 63;
    const int row = rb * 16 + (l & 15);
    const int k0 = ks * 32 + ((l >> 4) & 3) * 8;
    const int tok = seq[row], st = sub[row];
    const int p = row % SN;
    const float sp = sinf((float)p), cp = cosf((float)p);
    const float4 e0 = *(const float4*)&emb[(size_t)tok * DN + k0];
    const float4 e1 = *(const float4*)&emb[(size_t)tok * DN + k0 + 4];
    const float4 s0 = *(const float4*)&subg[(size_t)st * DN + k0];
    const float4 s1 = *(const float4*)&subg[(size_t)st * DN + k0 + 4];
    float xs[8] = {e0.x + s0.x, e0.y + s0.y, e0.z + s0.z, e0.w + s0.w,
                   e1.x + s1.x, e1.y + s1.y, e1.z + s1.z, e1.w + s1.w};
    bf16x8 o;
#pragma unroll
    for (int j = 0; j < 8; ++j)          // k0 even: j even -> sin, odd -> cos
        o[j] = f2bf(xs[j] + ((j & 1) ? cp : sp));
    *(bf16x8*)&xa[((size_t)(rb * 4 + ks) * 64 + l) * 8] = o;
}

// ---------------------------------------------------------------------------
// k_qkv: MFMA projections.  grid 392, block 256; wave = 32 rows x 128 cols.
// A-frags from global (xa), B-frags from global (pw, L2-hot).
// Writes Q,K,V bf16 row-major [BSN][128].
// ---------------------------------------------------------------------------
__global__ __launch_bounds__(256) void k_qkv(
    const short* __restrict__ xa, const short* __restrict__ pw,
    const float* __restrict__ bq, const float* __restrict__ bk,
    const float* __restrict__ bv,
    short* __restrict__ q, short* __restrict__ k, short* __restrict__ v)
{
    const int t = threadIdx.x, w = t >> 6, l = t & 63;
    const int rbw = blockIdx.x * 8 + w * 2;
    const bf16x8* A = (const bf16x8*)xa;
    const bf16x8* B = (const bf16x8*)pw;

    bf16x8 a[2][4];
#pragma unroll
    for (int mf = 0; mf < 2; ++mf)
#pragma unroll
        for (int ks = 0; ks < 4; ++ks)
            a[mf][ks] = A[((rbw + mf) * 4 + ks) * 64 + l];

    const float* Bias[3] = {bq, bk, bv};
    short*       Out[3]  = {q, k, v};
#pragma unroll
    for (int m = 0; m < 3; ++m) {
        f32x4 acc[2][8];
#pragma unroll
        for (int mf = 0; mf < 2; ++mf)
#pragma unroll
            for (int nf = 0; nf < 8; ++nf) acc[mf][nf] = (f32x4){0.f,0.f,0.f,0.f};
#pragma unroll
        for (int ks = 0; ks < 4; ++ks)
#pragma unroll
            for (int nf = 0; nf < 8; ++nf) {
                bf16x8 b = B[(m * 32 + nf * 4 + ks) * 64 + l];
                acc[0][nf] = __builtin_amdgcn_mfma_f32_16x16x32_bf16(a[0][ks], b, acc[0][nf], 0, 0, 0);
                acc[1][nf] = __builtin_amdgcn_mfma_f32_16x16x32_bf16(a[1][ks], b, acc[1][nf], 0, 0, 0);
            }
#pragma unroll
        for (int nf = 0; nf < 8; ++nf) {
            int col = nf * 16 + (l & 15);
            float bias = Bias[m][col];
#pragma unroll
            for (int mf = 0; mf < 2; ++mf) {
                int row = (rbw + mf) * 16 + ((l >> 4) << 2);
#pragma unroll
                for (int i = 0; i < 4; ++i)
                    Out[m][(size_t)(row + i) * DN + col] = f2bf(acc[mf][nf][i] + bias);
            }
        }
    }
}

// ---------------------------------------------------------------------------
// k_attn: block = batch (256 thr), wave = head.  Lane = query row; scores and
// softmax fully in registers; K/V broadcast from LDS fp32.
// Output av written directly in bf16 A-frag order.
// ---------------------------------------------------------------------------
__global__ __launch_bounds__(256) void k_attn(
    const short* __restrict__ qg, const short* __restrict__ kg,
    const short* __restrict__ vg, const int* __restrict__ seq,
    short* __restrict__ ava)
{
    __shared__ float kv[HN][2][SN * 32];   // 50.2 KB
    __shared__ int ss[SN];
    const int b = blockIdx.x, t = threadIdx.x;
    const int w = t >> 6, l = t & 63;
    const size_t base = (size_t)(b * SN) * DN + w * 32;

    if (t < SN) ss[t] = seq[b * SN + t];
    for (int idx = l; idx < SN * 4; idx += 64) {
        int c = idx >> 2, o = idx & 3;
        bf16x8 uk = *(const bf16x8*)&kg[base + (size_t)c * DN + o * 8];
        bf16x8 uv = *(const bf16x8*)&vg[base + (size_t)c * DN + o * 8];
        f32x4 k0 = {bf2f(uk[0]), bf2f(uk[1]), bf2f(uk[2]), bf2f(uk[3])};
        f32x4 k1 = {bf2f(uk[4]), bf2f(uk[5]), bf2f(uk[6]), bf2f(uk[7])};
        f32x4 v0 = {bf2f(uv[0]), bf2f(uv[1]), bf2f(uv[2]), bf2f(uv[3])};
        f32x4 v1 = {bf2f(uv[4]), bf2f(uv[5]), bf2f(uv[6]), bf2f(uv[7])};
        *(f32x4*)&kv[w][0][c * 32 + o * 8]     = k0;
        *(f32x4*)&kv[w][0][c * 32 + o * 8 + 4] = k1;
        *(f32x4*)&kv[w][1][c * 32 + o * 8]     = v0;
        *(f32x4*)&kv[w][1][c * 32 + o * 8 + 4] = v1;
    }
    float qr[32];
    if (l < SN) {
#pragma unroll
        for (int o = 0; o < 4; ++o) {
            bf16x8 u = *(const bf16x8*)&qg[base + (size_t)l * DN + o * 8];
#pragma unroll
            for (int j = 0; j < 8; ++j) qr[o * 8 + j] = bf2f(u[j]);
        }
    }
    __syncthreads();
    if (l >= SN) return;

    const bool rp = (ss[l] == 0);
    float sc[SN];
    float mx = -3.4e38f;
#pragma unroll
    for (int c = 0; c < SN; ++c) {
        float acm = 0.f;
#pragma unroll
        for (int o = 0; o < 8; ++o) {
            f32x4 kk = *(const f32x4*)&kv[w][0][c * 32 + o * 4];
            acm += qr[o*4+0]*kk[0] + qr[o*4+1]*kk[1] + qr[o*4+2]*kk[2] + qr[o*4+3]*kk[3];
        }
        acm *= (1.f / 32.f);
        acm = (rp || ss[c] == 0) ? NEGF : acm;
        sc[c] = acm;
        mx = fmaxf(mx, acm);
    }
    float sum = 0.f;
#pragma unroll
    for (int c = 0; c < SN; ++c) { float e = __expf(sc[c] - mx); sc[c] = e; sum += e; }
    const float inv = 1.f / sum;

    float ov[32];
#pragma unroll
    for (int d = 0; d < 32; ++d) ov[d] = 0.f;
#pragma unroll
    for (int c = 0; c < SN; ++c) {
        float p = sc[c] * inv;
#pragma unroll
        for (int o = 0; o < 8; ++o) {
            f32x4 vv = *(const f32x4*)&kv[w][1][c * 32 + o * 4];
            ov[o*4+0] += p * vv[0]; ov[o*4+1] += p * vv[1];
            ov[o*4+2] += p * vv[2]; ov[o*4+3] += p * vv[3];
        }
    }
    // write av in A-frag order: row = b*SN+l, k = w*32 + d
    const int row = b * SN + l;
    const int fbase = ((row >> 4) * 4 + w) * 512;
#pragma unroll
    for (int o = 0; o < 4; ++o) {
        bf16x8 u;
#pragma unroll
        for (int j = 0; j < 8; ++j) u[j] = f2bf(ov[o * 8 + j]);
        *(bf16x8*)&ava[fbase + (o * 16 + (row & 15)) * 8] = u;
    }
}

// ---------------------------------------------------------------------------
// k_enc: enc = av @ wo + bo via MFMA.  grid 392, block 256; fp32 row-major out.
// ---------------------------------------------------------------------------
__global__ __launch_bounds__(256) void k_enc(
    const short* __restrict__ ava, const short* __restrict__ pw,
    const float* __restrict__ bo, float* __restrict__ enc)
{
    const int t = threadIdx.x, w = t >> 6, l = t & 63;
    const int rbw = blockIdx.x * 8 + w * 2;
    const bf16x8* A = (const bf16x8*)ava;
    const bf16x8* B = (const bf16x8*)(pw + 3 * 32 * 512);   // wo

    f32x4 acc[2][8];
#pragma unroll
    for (int mf = 0; mf < 2; ++mf)
#pragma unroll
        for (int nf = 0; nf < 8; ++nf) acc[mf][nf] = (f32x4){0.f,0.f,0.f,0.f};
#pragma unroll
    for (int ks = 0; ks < 4; ++ks) {
        bf16x8 a0 = A[((rbw + 0) * 4 + ks) * 64 + l];
        bf16x8 a1 = A[((rbw + 1) * 4 + ks) * 64 + l];
#pragma unroll
        for (int nf = 0; nf < 8; ++nf) {
            bf16x8 b = B[(nf * 4 + ks) * 64 + l];
            acc[0][nf] = __builtin_amdgcn_mfma_f32_16x16x32_bf16(a0, b, acc[0][nf], 0, 0, 0);
            acc[1][nf] = __builtin_amdgcn_mfma_f32_16x16x32_bf16(a1, b, acc[1][nf], 0, 0, 0);
        }
    }
#pragma unroll
    for (int nf = 0; nf < 8; ++nf) {
        int col = nf * 16 + (l & 15);
        float bias = bo[col];
#pragma unroll
        for (int mf = 0; mf < 2; ++mf) {
            int row = (rbw + mf) * 16 + ((l >> 4) << 2);
#pragma unroll
            for (int i = 0; i < 4; ++i)
                enc[(size_t)(row + i) * DN + col] = acc[mf][nf][i] + bias;
        }
    }
}

// ---------------------------------------------------------------------------
// k_pool: per batch: w = enc@w_enc+b_enc; pooled -> bf16 A-frag.  grid 1024.
// ---------------------------------------------------------------------------
__global__ __launch_bounds__(128) void k_pool(
    const float* __restrict__ enc, const float* __restrict__ wenc,
    const float* __restrict__ benc, short* __restrict__ pa)
{
    __shared__ float es[SN][132];
    __shared__ float wrow[SN];
    const int b = blockIdx.x, t = threadIdx.x;
    for (int idx = t; idx < SN * 32; idx += 128) {
        int s = idx >> 5, o = idx & 31;
        *(float4*)&es[s][o * 4] = *(const float4*)&enc[(size_t)(b * SN + s) * DN + o * 4];
    }
    __syncthreads();
    if (t < SN) {
        float a = benc[0];
        for (int d = 0; d < DN; ++d) a += es[t][d] * wenc[d];
        wrow[t] = a;
    }
    __syncthreads();
    {
        float a = 0.f;
        for (int s = 0; s < SN; ++s) a += wrow[s] * es[s][t];
        int frag = (b >> 4) * 4 + (t >> 5);
        int lane = ((t >> 3) & 3) * 16 + (b & 15);
        pa[frag * 512 + lane * 8 + (t & 7)] = f2bf(a);
    }
}

// ---------------------------------------------------------------------------
// k_prepw: w_score fp32 [128][VN] -> bf16 B-frag, zero-padded.  grid 6252.
// ---------------------------------------------------------------------------
__global__ __launch_bounds__(256) void k_prepw(
    const float* __restrict__ wsc, short* __restrict__ pf)
{
    const int bx = blockIdx.x, t = threadIdx.x;
    const int c = bx * 16 + (t & 15);
    bf16x8 s;
#pragma unroll
    for (int j = 0; j < 8; ++j) {
        int k = (t >> 4) * 8 + j;
        float v = (c < VN) ? wsc[(size_t)k * VN + c] : 0.f;
        s[j] = f2bf(v);
    }
    const int base = (bx * 4 + (t >> 6)) * 512 + ((t >> 4) & 3) * 128 + (t & 15) * 8;
    *(bf16x8*)(pf + base) = s;
}

// ---------------------------------------------------------------------------
// k_novel: out = pooled @ w_score + b_score.  grid 1563, block 256.
// B-tile (64 cols x 128 k = 16 KB) staged in LDS once; loop all 8 row-groups
// -> w_score L3 traffic cut 8x vs gridded row-blocks.
// ---------------------------------------------------------------------------
__global__ __launch_bounds__(256) void k_novel(
    const short* __restrict__ pa, const short* __restrict__ pf,
    const float* __restrict__ bsc, float* __restrict__ out)
{
    __shared__ short bl[16 * 512];    // 16 KB
    const int t = threadIdx.x, w = t >> 6, l = t & 63;
    const int bx = blockIdx.x;

    const bf16x8* src = (const bf16x8*)(pf + (size_t)bx * 16 * 512);
    bf16x8* dst = (bf16x8*)bl;
    for (int i = t; i < 1024; i += 256) dst[i] = src[i];
    __syncthreads();

    const int cb = bx * 64 + (l & 15);
    float bias[4];
#pragma unroll
    for (int nf = 0; nf < 4; ++nf) {
        int col = cb + nf * 16;
        bias[nf] = (col < VN) ? bsc[col] : 0.f;
    }
    const bf16x8* A = (const bf16x8*)pa;
    const bf16x8* B = (const bf16x8*)bl;

    for (int rb8 = 0; rb8 < 8; ++rb8) {
        const int f0 = ((rb8 * 8 + w * 2) * 4) * 64 + l;   // mf stride 256, ks stride 64
        f32x4 acc[2][4];
#pragma unroll
        for (int mf = 0; mf < 2; ++mf)
#pragma unroll
            for (int nf = 0; nf < 4; ++nf) acc[mf][nf] = (f32x4){0.f,0.f,0.f,0.f};
#pragma unroll
        for (int ks = 0; ks < 4; ++ks) {
            bf16x8 a0 = A[f0 + ks * 64];
            bf16x8 a1 = A[f0 + 256 + ks * 64];
#pragma unroll
            for (int nf = 0; nf < 4; ++nf) {
                bf16x8 b = B[(nf * 4 + ks) * 64 + l];
                acc[0][nf] = __builtin_amdgcn_mfma_f32_16x16x32_bf16(a0, b, acc[0][nf], 0, 0, 0);
                acc[1][nf] = __builtin_amdgcn_mfma_f32_16x16x32_bf16(a1, b, acc[1][nf], 0, 0, 0);
            }
        }
        const int rb_ = rb8 * 128 + w * 32 + ((l >> 4) << 2);
#pragma unroll
        for (int nf = 0; nf < 4; ++nf) {
            int col = cb + nf * 16;
            if (col >= VN) continue;
#pragma unroll
            for (int mf = 0; mf < 2; ++mf) {
                int row = rb_ + mf * 16;
#pragma unroll
                for (int i = 0; i < 4; ++i)
                    out[(size_t)(row + i) * VN + col] = acc[mf][nf][i] + bias[nf];
            }
        }
    }
}

// ---------------------------------------------------------------------------
// k_mask: out[b][seq[b][s]] = NEG
// ---------------------------------------------------------------------------
__global__ __launch_bounds__(64) void k_mask(
    const int* __restrict__ seq, float* __restrict__ out)
{
    const int b = blockIdx.x, tid = threadIdx.x;
    if (tid < SN) {
        int t = seq[b * SN + tid];
        out[(size_t)b * VN + t] = NEGF;
    }
}

// ---------------------------------------------------------------------------
extern "C" void kernel_launch(void* const* d_in, const int* in_sizes, int n_in,
                              void* d_out, int out_size, void* d_ws, size_t ws_size,
                              hipStream_t stream)
{
    (void)in_sizes; (void)n_in; (void)out_size; (void)ws_size;
    const int*   seq  = (const int*)d_in[0];
    const int*   sub  = (const int*)d_in[1];
    const float* emb  = (const float*)d_in[2];
    const float* subg = (const float*)d_in[3];
    const float* wq   = (const float*)d_in[4];
    const float* bq   = (const float*)d_in[5];
    const float* wk   = (const float*)d_in[6];
    const float* bk   = (const float*)d_in[7];
    const float* wv   = (const float*)d_in[8];
    const float* bv   = (const float*)d_in[9];
    const float* wo   = (const float*)d_in[10];
    const float* bo   = (const float*)d_in[11];
    const float* wenc = (const float*)d_in[12];
    const float* benc = (const float*)d_in[13];
    const float* wsc  = (const float*)d_in[14];
    const float* bsc  = (const float*)d_in[15];
    float* out = (float*)d_out;

    const size_t NBSD = (size_t)BSN * DN;       // 6,422,528
    short* XA  = (short*)d_ws;                  // bf16 A-frags of x
    short* Qg  = XA  + NBSD;                    // bf16 row-major QKV
    short* Kg  = Qg  + NBSD;
    short* Vg  = Kg  + NBSD;
    short* AVA = Vg  + NBSD;                    // bf16 A-frags of av
    short* PW4 = AVA + NBSD;                    // 4 x 128 x 128 B-frags
    short* PA  = PW4 + 4 * 32 * 512;            // pooled A-frags
    short* PF  = PA  + (size_t)BN * DN;         // w_score B-frags (25.6 MB)
    float* ENC = (float*)(PF + (size_t)6252 * 4 * 512);  // fp32 row-major enc

    k_prepw4<<<32, 256, 0, stream>>>(wq, wk, wv, wo, PW4);
    k_embed<<<RBN, 256, 0, stream>>>(seq, sub, emb, subg, XA);
    k_qkv<<<392, 256, 0, stream>>>(XA, PW4, bq, bk, bv, Qg, Kg, Vg);
    k_attn<<<BN, 256, 0, stream>>>(Qg, Kg, Vg, seq, AVA);
    k_enc<<<392, 256, 0, stream>>>(AVA, PW4, bo, ENC);
    k_pool<<<BN, 128, 0, stream>>>(ENC, wenc, benc, PA);
    k_prepw<<<6252, 256, 0, stream>>>(wsc, PF);
    k_novel<<<1563, 256, 0, stream>>>(PA, PF, bsc, out);
    k_mask<<<BN, 64, 0, stream>>>(seq, out);
}